// Round 20
// baseline (708.685 us; speedup 1.0000x reference)
//
#include <hip/hip_runtime.h>
#include <hip/hip_bf16.h>

#define T_ 35
#define B_ 128
#define E_ 200
#define H_ 512
#define L_ 2
#define V_ 10000
#define BH_ (B_ * H_)
#define KPAD 224
#define NCL 4            // independent row clusters (32 rows each)
#define CLW 48           // WGs per cluster (16 L0 + 32 L1)
#define NWG (NCL * CLW)  // 192

typedef __attribute__((ext_vector_type(8))) short bf16x8;
typedef __attribute__((ext_vector_type(4))) float f32x4;

__device__ __forceinline__ unsigned short f2bf(float f) {
    union { float f; unsigned u; } c; c.f = f;
    unsigned r = c.u + 0x7FFF + ((c.u >> 16) & 1);
    return (unsigned short)(r >> 16);
}
__device__ __forceinline__ float bf2f(unsigned short u) {
    union { unsigned u; float f; } c; c.u = ((unsigned)u) << 16; return c.f;
}

__device__ __forceinline__ bf16x8 cvt8(const float* src) {
    float4 w0 = *(const float4*)src;
    float4 w1 = *(const float4*)(src + 4);
    bf16x8 v;
    v[0] = (short)f2bf(w0.x); v[1] = (short)f2bf(w0.y);
    v[2] = (short)f2bf(w0.z); v[3] = (short)f2bf(w0.w);
    v[4] = (short)f2bf(w1.x); v[5] = (short)f2bf(w1.y);
    v[6] = (short)f2bf(w1.z); v[7] = (short)f2bf(w1.w);
    return v;
}

// quad-pack bf16 -> one 8B relaxed agent-scope store (MALL-bypass).
__device__ __forceinline__ void store_quad_bf16(unsigned short* buf, int idx,
                                                float v, int lane) {
    unsigned x = (unsigned)f2bf(v);
    unsigned y = (unsigned)__shfl_xor((int)x, 1);
    unsigned pair = (lane & 1) ? (y | (x << 16)) : (x | (y << 16));
    unsigned long long q = (unsigned long long)pair;
    unsigned long long p2 = (unsigned long long)(unsigned)__shfl_xor((int)pair, 2);
    unsigned long long quad = (lane & 2) ? (p2 | (q << 32)) : (q | (p2 << 32));
    if ((lane & 3) == 0)
        __hip_atomic_store((unsigned long long*)(buf + idx), quad,
                           __ATOMIC_RELAXED, __HIP_MEMORY_SCOPE_AGENT);
}

// pair-pack 2 f32 (adjacent lanes = adjacent cols) -> 8B agent store.
// Bypasses L2 write-allocate: no RFO fetch on the C output stream.
__device__ __forceinline__ void store_pair_f32(float* buf, size_t idx,
                                               float v, int lane) {
    union { float f; unsigned u; } c0, c1;
    c0.f = v;
    c1.u = (unsigned)__shfl_xor((int)c0.u, 1);
    if ((lane & 1) == 0) {
        unsigned long long q = (unsigned long long)c0.u |
                               ((unsigned long long)c1.u << 32);
        __hip_atomic_store((unsigned long long*)(buf + idx), q,
                           __ATOMIC_RELAXED, __HIP_MEMORY_SCOPE_AGENT);
    }
}

// ---------------------------------------------------------------- prep
__global__ void prep_all(const float* __restrict__ emb, const float* __restrict__ Wx0,
                         const float* __restrict__ hidden, const float* __restrict__ Wout,
                         unsigned short* embB, unsigned short* wx0cat,
                         unsigned short* WoutB,
                         unsigned short* h0bt, unsigned short* h1bfx, int* flags) {
    int job = blockIdx.y;
    int stride = gridDim.x * blockDim.x;
    int i0 = blockIdx.x * blockDim.x + threadIdx.x;
    if (job == 0) {
        for (int i = i0; i < V_ * KPAD; i += stride) {
            int v = i / KPAD, k = i - v * KPAD;
            embB[i] = (k < E_) ? f2bf(emb[v * E_ + k]) : (unsigned short)0;
        }
    } else if (job == 1) {
        for (int i = i0; i < 1536 * KPAD; i += stride) {
            int n = i / KPAD, k = i - n * KPAD;
            wx0cat[i] = (k < E_) ? f2bf(Wx0[n * E_ + k]) : (unsigned short)0;
        }
    } else if (job == 2) {
        for (int i = i0; i < 2 * BH_; i += stride) {
            if (i < BH_) h0bt[i] = f2bf(hidden[i]);
            else         h1bfx[i - BH_] = f2bf(hidden[i]);
        }
        for (int i = i0; i < NWG * 32; i += stride) flags[i] = 0;
    } else {
        for (int i = i0; i < V_ * H_; i += stride) WoutB[i] = f2bf(Wout[i]);
    }
}

// ---------------------------------------------------------------- x-side GEMM
__global__ __launch_bounds__(256) void xside_gemm(
    const int* __restrict__ inputs, const unsigned short* __restrict__ embB,
    const unsigned short* __restrict__ wx0cat, float* __restrict__ gx0) {
    int m0 = blockIdx.x * 128, n0 = blockIdx.y * 128;
    int wave = threadIdx.x >> 6, lane = threadIdx.x & 63;
    int wr = wave >> 1, wc = wave & 1;
    int am = m0 + wr * 64, bn = n0 + wc * 64;
    int lr = lane & 15, lk = (lane >> 4) * 8;

    f32x4 acc[4][4] = {};
    int id[4];
    #pragma unroll
    for (int i = 0; i < 4; ++i) id[i] = inputs[am + i * 16 + lr];

    for (int k0 = 0; k0 < KPAD; k0 += 32) {
        bf16x8 a[4], b[4];
        #pragma unroll
        for (int i = 0; i < 4; ++i)
            a[i] = *(const bf16x8*)(embB + (size_t)id[i] * KPAD + k0 + lk);
        #pragma unroll
        for (int j = 0; j < 4; ++j)
            b[j] = *(const bf16x8*)(wx0cat + (size_t)(bn + j * 16 + lr) * KPAD + k0 + lk);
        #pragma unroll
        for (int i = 0; i < 4; ++i)
            #pragma unroll
            for (int j = 0; j < 4; ++j)
                acc[i][j] = __builtin_amdgcn_mfma_f32_16x16x32_bf16(a[i], b[j], acc[i][j], 0, 0, 0);
    }
    int crow0 = (lane >> 4) * 4, ccol = lane & 15;
    #pragma unroll
    for (int i = 0; i < 4; ++i) {
        #pragma unroll
        for (int r = 0; r < 4; ++r) {
            int row = am + i * 16 + crow0 + r;
            int t = row >> 7, b = row & 127;
            #pragma unroll
            for (int j = 0; j < 4; ++j) {
                int col = bn + j * 16 + ccol;
                int g = col >> 9, h = col & 511;
                gx0[((size_t)(t * 3 + g) * 128 + b) * 512 + h] = acc[i][j][r];
            }
        }
    }
}

// ---------------------------------------------------------------- scan (r16)
__device__ __forceinline__ void bar_l0(int* flb, int wgl, int gen) {
    __syncthreads();
    if (threadIdx.x == 0)
        __hip_atomic_store(flb + wgl * 32, gen,
                           __ATOMIC_RELAXED, __HIP_MEMORY_SCOPE_AGENT);
    if (threadIdx.x < 16) {
        while (__hip_atomic_load(flb + threadIdx.x * 32, __ATOMIC_RELAXED,
                                 __HIP_MEMORY_SCOPE_AGENT) < gen)
            __builtin_amdgcn_s_sleep(1);
    }
    __syncthreads();
}

__device__ __forceinline__ void bar_l1(int* flb, int wid, int gen, int l0need) {
    __syncthreads();
    if (threadIdx.x == 0)
        __hip_atomic_store(flb + (16 + wid) * 32, gen,
                           __ATOMIC_RELAXED, __HIP_MEMORY_SCOPE_AGENT);
    if (threadIdx.x < 32) {
        while (__hip_atomic_load(flb + (16 + threadIdx.x) * 32, __ATOMIC_RELAXED,
                                 __HIP_MEMORY_SCOPE_AGENT) < gen)
            __builtin_amdgcn_s_sleep(1);
    } else if (threadIdx.x < 48) {
        while (__hip_atomic_load(flb + (threadIdx.x - 32) * 32, __ATOMIC_RELAXED,
                                 __HIP_MEMORY_SCOPE_AGENT) < l0need)
            __builtin_amdgcn_s_sleep(1);
    }
    __syncthreads();
}

__global__ __launch_bounds__(512) void scan_kernel(
    const float* __restrict__ gx0,
    const float* __restrict__ Wx, const float* __restrict__ Wh,
    const float* __restrict__ bh, const float* __restrict__ hidden,
    unsigned short* h0bt, unsigned short* rh0t, unsigned short* rh1t,
    unsigned short* h1bfx, int* flags, float* hfinal_out) {
    __shared__ unsigned short wlds[96 * 512];   // 96 KB

    const int tid = threadIdx.x;
    const int bx = blockIdx.x;
    const int cl = bx & 3;
    const int wgl = bx >> 2;
    const int lane = tid & 63;
    const int wave = tid >> 6;
    const int lr = lane & 15;
    const int hi = lane >> 4;
    const int lk8 = hi * 8;
    const int ccol = lane & 15;
    const int crow0 = hi * 4;
    const int R0 = cl * 32;

    const bool isL0 = (wgl < 16);
    const int wid = wgl - 16;
    int* flb = flags + cl * CLW * 32;

    if (isL0) {
        for (int i = tid; i < 96 * 64; i += 512) {
            int lc = i >> 6, kg = i & 63;
            int g = lc >> 5, h = (wgl << 5) + (lc & 31);
            const float* src = Wh + (size_t)(g * 512 + h) * 512 + kg * 8;
            *(bf16x8*)(wlds + lc * 512 + (kg ^ (lc & 7)) * 8) = cvt8(src);
        }
    } else {
        for (int i = tid; i < 48 * 128; i += 512) {
            int lc = i >> 7, kg = i & 127;
            int g = lc >> 4, h = (wid << 4) + (lc & 15);
            const float* src = (kg < 64)
                ? Wx + (size_t)(g * 512 + h) * 512 + kg * 8
                : Wh + (size_t)(3 * 512 * 512) + (size_t)(g * 512 + h) * 512 + (kg - 64) * 8;
            *(bf16x8*)(wlds + lc * 1024 + (kg ^ (lc & 7)) * 8) = cvt8(src);
        }
    }

    const int mt0 = wave >> 2, nt0 = wave & 3;
    const int mt1 = (wave >> 1) & 1, nt1 = wave & 1;
    float h0reg[4], freg0[4], bias_p1_0 = 0.f, bias_p2_0 = 0.f;
    float h1reg[4], freg1[4], bias_p1_1 = 0.f, bias_p2_1 = 0.f;
    bf16x8 a0keep[16];

    if (isL0) {
        const int base = wgl << 5;
        int g = nt0 >> 1;
        int hp1 = base + (nt0 & 1) * 16 + ccol;
        bias_p1_0 = bh[g * 512 + hp1];
        if (nt0 >= 2) {
            int hc = base + (nt0 - 2) * 16 + ccol;
            int rowg = R0 + mt0 * 16;
            #pragma unroll
            for (int r = 0; r < 4; ++r)
                h0reg[r] = hidden[(size_t)(rowg + crow0 + r) * 512 + hc];
            bias_p2_0 = bh[1024 + hc];
        }
    } else {
        const int base = wid << 4;
        int hc = base + ccol;
        if (wave < 4) {
            bias_p1_1 = bh[1536 + nt1 * 512 + hc];
            if (nt1 == 1) {
                int rowg = R0 + mt1 * 16;
                #pragma unroll
                for (int r = 0; r < 4; ++r)
                    h1reg[r] = hidden[(size_t)BH_ + (size_t)(rowg + crow0 + r) * 512 + hc];
                bias_p2_1 = bh[2560 + hc];
            }
        }
    }
    __syncthreads();

    if (isL0) {
        const int base = wgl << 5;
        const int rowg = R0 + mt0 * 16;
        const int hP1 = base + (nt0 & 1) * 16 + ccol;
        const int gP1 = nt0 >> 1;
        const int ntp = (nt0 >= 2) ? (nt0 - 2) : 0;
        const int hP2 = base + ntp * 16 + ccol;

        float gxn[4];
        {
            const float* gx = gx0 + (size_t)(0 * 3 + gP1) * BH_ + hP1;
            #pragma unroll
            for (int r = 0; r < 4; ++r)
                gxn[r] = gx[(rowg + crow0 + r) * 512];
        }

        for (int s = 0; s < 2 * T_; ++s) {
            bar_l0(flb, wgl, s);
            int t = s >> 1;
            float gxc[4];
            #pragma unroll
            for (int r = 0; r < 4; ++r) gxc[r] = gxn[r];
            if (s + 1 < 2 * T_) {
                int tn = (s + 1) >> 1;
                const float* gx = (((s + 1) & 1) == 0)
                    ? gx0 + (size_t)(tn * 3 + gP1) * BH_ + hP1
                    : gx0 + (size_t)(tn * 3 + 2) * BH_ + hP2;
                #pragma unroll
                for (int r = 0; r < 4; ++r)
                    gxn[r] = gx[(rowg + crow0 + r) * 512];
            }
            if ((s & 1) == 0) {
                const unsigned short* hprev = h0bt + (size_t)t * BH_;
                unsigned short* rh0 = rh0t + (size_t)t * BH_;
                bf16x8 a[16];
                #pragma unroll
                for (int ks = 0; ks < 16; ++ks)
                    a[ks] = *(const bf16x8*)(hprev + (size_t)(rowg + lr) * 512 + ks * 32 + lk8);
                f32x4 accA = {0.f, 0.f, 0.f, 0.f}, accB = {0.f, 0.f, 0.f, 0.f};
                #pragma unroll
                for (int ks = 0; ks < 16; ks += 2) {
                    int c = nt0 * 16 + lr;
                    int kgA = 4 * ks + hi, kgB = 4 * (ks + 1) + hi;
                    bf16x8 bA = *(const bf16x8*)(wlds + c * 512 + (kgA ^ (c & 7)) * 8);
                    bf16x8 bB = *(const bf16x8*)(wlds + c * 512 + (kgB ^ (c & 7)) * 8);
                    accA = __builtin_amdgcn_mfma_f32_16x16x32_bf16(a[ks], bA, accA, 0, 0, 0);
                    accB = __builtin_amdgcn_mfma_f32_16x16x32_bf16(a[ks + 1], bB, accB, 0, 0, 0);
                }
                #pragma unroll
                for (int r = 0; r < 4; ++r) {
                    int b = rowg + crow0 + r;
                    float v = accA[r] + accB[r] + gxc[r] + bias_p1_0;
                    float sg = 1.f / (1.f + __expf(-v));
                    if (nt0 < 2) {
                        float h0p = bf2f(hprev[(size_t)b * 512 + hP1]);
                        store_quad_bf16(rh0, b * 512 + hP1 - (lane & 3), sg * h0p, lane);
                    } else {
                        freg0[r] = sg;
                    }
                }
            } else if (nt0 >= 2) {
                const unsigned short* rh0 = rh0t + (size_t)t * BH_;
                unsigned short* h0nx = h0bt + (size_t)(t + 1) * BH_;
                bf16x8 a[16];
                #pragma unroll
                for (int ks = 0; ks < 16; ++ks)
                    a[ks] = *(const bf16x8*)(rh0 + (size_t)(rowg + lr) * 512 + ks * 32 + lk8);
                f32x4 accA = {0.f, 0.f, 0.f, 0.f}, accB = {0.f, 0.f, 0.f, 0.f};
                #pragma unroll
                for (int ks = 0; ks < 16; ks += 2) {
                    int c = 64 + ntp * 16 + lr;
                    int kgA = 4 * ks + hi, kgB = 4 * (ks + 1) + hi;
                    bf16x8 bA = *(const bf16x8*)(wlds + c * 512 + (kgA ^ (c & 7)) * 8);
                    bf16x8 bB = *(const bf16x8*)(wlds + c * 512 + (kgB ^ (c & 7)) * 8);
                    accA = __builtin_amdgcn_mfma_f32_16x16x32_bf16(a[ks], bA, accA, 0, 0, 0);
                    accB = __builtin_amdgcn_mfma_f32_16x16x32_bf16(a[ks + 1], bB, accB, 0, 0, 0);
                }
                #pragma unroll
                for (int r = 0; r < 4; ++r) {
                    int b = rowg + crow0 + r;
                    float v = accA[r] + accB[r] + gxc[r] + bias_p2_0;
                    float tld = tanhf(v);
                    float hn = h0reg[r] + freg0[r] * (tld - h0reg[r]);
                    h0reg[r] = hn;
                    store_quad_bf16(h0nx, b * 512 + hP2 - (lane & 3), hn, lane);
                }
            }
        }
        __syncthreads();
        if (tid == 0)
            __hip_atomic_store(flb + wgl * 32, 2 * T_,
                               __ATOMIC_RELAXED, __HIP_MEMORY_SCOPE_AGENT);
        if (nt0 >= 2) {
            #pragma unroll
            for (int r = 0; r < 4; ++r)
                hfinal_out[(size_t)(rowg + crow0 + r) * 512 + hP2] = h0reg[r];
        }
    } else {
        for (int s = 0; s < 2 * T_; ++s) {
            int tc = s >> 1;
            int l0need = ((s & 1) == 0) ? (2 * tc + 2) : 0;
            bar_l1(flb, wid, s, l0need);
            if ((s & 1) == 0) {
                if (wave < 4) {
                    const int base = wid << 4;
                    const int rowg = R0 + mt1 * 16;
                    const unsigned short* h0cur = h0bt + (size_t)(tc + 1) * BH_;
                    const unsigned short* h1prev = h1bfx + (size_t)tc * BH_;
                    unsigned short* rh1 = rh1t + (size_t)tc * BH_;
                    bf16x8 a1[16];
                    #pragma unroll
                    for (int ks = 0; ks < 16; ++ks) {
                        a0keep[ks] = *(const bf16x8*)(h0cur + (size_t)(rowg + lr) * 512 + ks * 32 + lk8);
                        a1[ks] = *(const bf16x8*)(h1prev + (size_t)(rowg + lr) * 512 + ks * 32 + lk8);
                    }
                    f32x4 accA = {0.f, 0.f, 0.f, 0.f}, accB = {0.f, 0.f, 0.f, 0.f};
                    #pragma unroll
                    for (int ks = 0; ks < 16; ++ks) {
                        int kg = 4 * ks + hi;
                        int c = nt1 * 16 + lr;
                        bf16x8 b = *(const bf16x8*)(wlds + c * 1024 + (kg ^ (c & 7)) * 8);
                        accA = __builtin_amdgcn_mfma_f32_16x16x32_bf16(a0keep[ks], b, accA, 0, 0, 0);
                    }
                    #pragma unroll
                    for (int ks = 0; ks < 16; ++ks) {
                        int kg = 64 + 4 * ks + hi;
                        int c = nt1 * 16 + lr;
                        bf16x8 b = *(const bf16x8*)(wlds + c * 1024 + (kg ^ (c & 7)) * 8);
                        accB = __builtin_amdgcn_mfma_f32_16x16x32_bf16(a1[ks], b, accB, 0, 0, 0);
                    }
                    int h = base + ccol;
                    #pragma unroll
                    for (int r = 0; r < 4; ++r) {
                        int b = rowg + crow0 + r;
                        float v = accA[r] + accB[r] + bias_p1_1;
                        float sg = 1.f / (1.f + __expf(-v));
                        if (nt1 == 0) {
                            float h1p = bf2f(h1prev[(size_t)b * 512 + h]);
                            store_quad_bf16(rh1, b * 512 + h - (lane & 3), sg * h1p, lane);
                        } else {
                            freg1[r] = sg;
                        }
                    }
                }
            } else {
                if (wave < 4 && nt1 == 1) {
                    const int base = wid << 4;
                    const int rowg = R0 + mt1 * 16;
                    const unsigned short* rh1 = rh1t + (size_t)tc * BH_;
                    unsigned short* h1nx = h1bfx + (size_t)(tc + 1) * BH_;
                    bf16x8 a1[16];
                    #pragma unroll
                    for (int ks = 0; ks < 16; ++ks)
                        a1[ks] = *(const bf16x8*)(rh1 + (size_t)(rowg + lr) * 512 + ks * 32 + lk8);
                    f32x4 accA = {0.f, 0.f, 0.f, 0.f}, accB = {0.f, 0.f, 0.f, 0.f};
                    #pragma unroll
                    for (int ks = 0; ks < 16; ++ks) {
                        int kg = 4 * ks + hi;
                        int c = 32 + lr;
                        bf16x8 b = *(const bf16x8*)(wlds + c * 1024 + (kg ^ (c & 7)) * 8);
                        accA = __builtin_amdgcn_mfma_f32_16x16x32_bf16(a0keep[ks], b, accA, 0, 0, 0);
                    }
                    #pragma unroll
                    for (int ks = 0; ks < 16; ++ks) {
                        int kg = 64 + 4 * ks + hi;
                        int c = 32 + lr;
                        bf16x8 b = *(const bf16x8*)(wlds + c * 1024 + (kg ^ (c & 7)) * 8);
                        accB = __builtin_amdgcn_mfma_f32_16x16x32_bf16(a1[ks], b, accB, 0, 0, 0);
                    }
                    int h = base + ccol;
                    #pragma unroll
                    for (int r = 0; r < 4; ++r) {
                        int b = rowg + crow0 + r;
                        float v = accA[r] + accB[r] + bias_p2_1;
                        float tld = tanhf(v);
                        float hn = h1reg[r] + freg1[r] * (tld - h1reg[r]);
                        h1reg[r] = hn;
                        store_quad_bf16(h1nx, b * 512 + h - (lane & 3), hn, lane);
                    }
                }
            }
        }
        if (wave < 4 && nt1 == 1) {
            const int base = wid << 4;
            int rowg = R0 + mt1 * 16;
            #pragma unroll
            for (int r = 0; r < 4; ++r)
                hfinal_out[(size_t)BH_ + (size_t)(rowg + crow0 + r) * 512 + base + ccol] = h1reg[r];
        }
    }
}

// ---------------------------------------------------------------- logits
// 256x128 tiles (8 waves = 4m x 2n, each the r19 64x64 schedule): halves
// block count (1422) and redundant A-panel reads; RFO-free paired C stores.
#define MT_ ((T_ * B_ + 255) / 256)  // 18 m-tiles (last is half)
#define NT_ ((V_ + 127) / 128)       // 79 n-tiles
__global__ __launch_bounds__(512) void logits_gemm(
    const unsigned short* __restrict__ A, const unsigned short* __restrict__ Bw,
    const float* __restrict__ bout, float* __restrict__ C) {
    const int nwg = MT_ * NT_;       // 1422
    const int q = nwg / 8, rr = nwg % 8;
    int bid = blockIdx.x;
    int xcd = bid % 8, idx = bid / 8;
    int wgid = (xcd < rr ? xcd * (q + 1) : rr * (q + 1) + (xcd - rr) * q) + idx;
    int n0 = (wgid / MT_) * 128;
    int m0 = (wgid % MT_) * 256;

    int wave = threadIdx.x >> 6, lane = threadIdx.x & 63;
    int wr = wave >> 1, wc = wave & 1;   // 4m x 2n wave grid
    int am = m0 + wr * 64, bn = n0 + wc * 64;
    int lr = lane & 15, lk = (lane >> 4) * 8;

    f32x4 acc[4][4] = {};
    bf16x8 a[4], b[4], an[4], bnx[4];
    #pragma unroll
    for (int i = 0; i < 4; ++i) {
        int row = am + i * 16 + lr; if (row >= T_ * B_) row = T_ * B_ - 1;
        a[i] = *(const bf16x8*)(A + (size_t)row * H_ + lk);
    }
    #pragma unroll
    for (int j = 0; j < 4; ++j) {
        int colc = bn + j * 16 + lr; if (colc >= V_) colc = V_ - 1;
        b[j] = *(const bf16x8*)(Bw + (size_t)colc * H_ + lk);
    }
    for (int k0 = 0; k0 < H_; k0 += 32) {
        if (k0 + 32 < H_) {
            #pragma unroll
            for (int i = 0; i < 4; ++i) {
                int row = am + i * 16 + lr; if (row >= T_ * B_) row = T_ * B_ - 1;
                an[i] = *(const bf16x8*)(A + (size_t)row * H_ + k0 + 32 + lk);
            }
            #pragma unroll
            for (int j = 0; j < 4; ++j) {
                int colc = bn + j * 16 + lr; if (colc >= V_) colc = V_ - 1;
                bnx[j] = *(const bf16x8*)(Bw + (size_t)colc * H_ + k0 + 32 + lk);
            }
        }
        #pragma unroll
        for (int i = 0; i < 4; ++i)
            #pragma unroll
            for (int j = 0; j < 4; ++j)
                acc[i][j] = __builtin_amdgcn_mfma_f32_16x16x32_bf16(a[i], b[j], acc[i][j], 0, 0, 0);
        #pragma unroll
        for (int i = 0; i < 4; ++i) { a[i] = an[i]; b[i] = bnx[i]; }
    }
    int crow0 = (lane >> 4) * 4, ccol = lane & 15;
    // V_=10000 even, pair cols never straddle the tail; row uniform per pair.
    #pragma unroll
    for (int j = 0; j < 4; ++j) {
        int col = bn + j * 16 + ccol;
        if (col >= V_) continue;
        float bv = bout[col];
        #pragma unroll
        for (int i = 0; i < 4; ++i) {
            #pragma unroll
            for (int r = 0; r < 4; ++r) {
                int row = am + i * 16 + crow0 + r;
                if (row < T_ * B_)
                    store_pair_f32(C, (size_t)row * V_ + (col & ~1),
                                   acc[i][j][r] + bv, lane);
            }
        }
    }
}

// ---------------------------------------------------------------- launch
extern "C" void kernel_launch(void* const* d_in, const int* in_sizes, int n_in,
                              void* d_out, int out_size, void* d_ws, size_t ws_size,
                              hipStream_t stream) {
    const int*   inputs = (const int*)  d_in[0];
    const float* hidden = (const float*)d_in[1];
    const float* emb    = (const float*)d_in[2];
    const float* Wx0    = (const float*)d_in[3];
    const float* Wx     = (const float*)d_in[4];
    const float* Wh     = (const float*)d_in[5];
    const float* bh     = (const float*)d_in[6];
    const float* Wout   = (const float*)d_in[7];
    const float* bout   = (const float*)d_in[8];
    float* out = (float*)d_out;
    (void)in_sizes; (void)n_in; (void)out_size; (void)ws_size;

    char* ws = (char*)d_ws;
    size_t off = 0;
    auto alloc = [&](size_t bytes) -> void* {
        void* p = ws + off;
        off += (bytes + 255) & ~(size_t)255;
        return p;
    };
    unsigned short* embB   = (unsigned short*)alloc((size_t)V_ * KPAD * 2);
    unsigned short* wx0cat = (unsigned short*)alloc((size_t)1536 * KPAD * 2);
    unsigned short* WoutB  = (unsigned short*)alloc((size_t)V_ * H_ * 2);
    unsigned short* h1bfx  = (unsigned short*)alloc((size_t)(T_ + 1) * BH_ * 2);
    int* flags = (int*)alloc(NWG * 32 * 4);

    float* gx0 = out;
    unsigned short* scr = (unsigned short*)(out + (size_t)T_ * 3 * BH_);
    unsigned short* h0bt = scr;                                   // 36*BH
    unsigned short* rh0t = scr + (size_t)(T_ + 1) * BH_;          // 35*BH
    unsigned short* rh1t = scr + (size_t)(2 * T_ + 1) * BH_;      // 35*BH

    prep_all<<<dim3(1024, 4), dim3(256), 0, stream>>>(
        emb, Wx0, hidden, Wout, embB, wx0cat, WoutB, h0bt, h1bfx, flags);
    xside_gemm<<<dim3(T_, 12), dim3(256), 0, stream>>>(inputs, embB, wx0cat, gx0);
    scan_kernel<<<dim3(NWG), dim3(512), 0, stream>>>(
        gx0, Wx, Wh, bh, hidden,
        h0bt, rh0t, rh1t, h1bfx, flags,
        out + (size_t)T_ * B_ * V_);
    logits_gemm<<<dim3(MT_ * NT_), dim3(512), 0, stream>>>(
        h1bfx + BH_, WoutB, bout, out);
}

// Round 21
// 574.815 us; speedup vs baseline: 1.2329x; 1.2329x over previous
//
#include <hip/hip_runtime.h>
#include <hip/hip_bf16.h>

#define T_ 35
#define B_ 128
#define E_ 200
#define H_ 512
#define L_ 2
#define V_ 10000
#define BH_ (B_ * H_)
#define KPAD 224
#define NCL 4            // independent row clusters (32 rows each)
#define CLW 48           // WGs per cluster (16 L0 + 32 L1)
#define NWG (NCL * CLW)  // 192

typedef __attribute__((ext_vector_type(8))) short bf16x8;
typedef __attribute__((ext_vector_type(4))) float f32x4;

__device__ __forceinline__ unsigned short f2bf(float f) {
    union { float f; unsigned u; } c; c.f = f;
    unsigned r = c.u + 0x7FFF + ((c.u >> 16) & 1);
    return (unsigned short)(r >> 16);
}
__device__ __forceinline__ float bf2f(unsigned short u) {
    union { unsigned u; float f; } c; c.u = ((unsigned)u) << 16; return c.f;
}

__device__ __forceinline__ bf16x8 cvt8(const float* src) {
    float4 w0 = *(const float4*)src;
    float4 w1 = *(const float4*)(src + 4);
    bf16x8 v;
    v[0] = (short)f2bf(w0.x); v[1] = (short)f2bf(w0.y);
    v[2] = (short)f2bf(w0.z); v[3] = (short)f2bf(w0.w);
    v[4] = (short)f2bf(w1.x); v[5] = (short)f2bf(w1.y);
    v[6] = (short)f2bf(w1.z); v[7] = (short)f2bf(w1.w);
    return v;
}

// quad-pack bf16 -> one 8B relaxed agent-scope store (MALL-bypass).
__device__ __forceinline__ void store_quad_bf16(unsigned short* buf, int idx,
                                                float v, int lane) {
    unsigned x = (unsigned)f2bf(v);
    unsigned y = (unsigned)__shfl_xor((int)x, 1);
    unsigned pair = (lane & 1) ? (y | (x << 16)) : (x | (y << 16));
    unsigned long long q = (unsigned long long)pair;
    unsigned long long p2 = (unsigned long long)(unsigned)__shfl_xor((int)pair, 2);
    unsigned long long quad = (lane & 2) ? (p2 | (q << 32)) : (q | (p2 << 32));
    if ((lane & 3) == 0)
        __hip_atomic_store((unsigned long long*)(buf + idx), quad,
                           __ATOMIC_RELAXED, __HIP_MEMORY_SCOPE_AGENT);
}

// pair-pack 2 f32 (adjacent lanes = adjacent cols) -> 8B agent store.
// Bypasses L2 write-allocate: no RFO fetch on the C output stream.
__device__ __forceinline__ void store_pair_f32(float* buf, size_t idx,
                                               float v, int lane) {
    union { float f; unsigned u; } c0, c1;
    c0.f = v;
    c1.u = (unsigned)__shfl_xor((int)c0.u, 1);
    if ((lane & 1) == 0) {
        unsigned long long q = (unsigned long long)c0.u |
                               ((unsigned long long)c1.u << 32);
        __hip_atomic_store((unsigned long long*)(buf + idx), q,
                           __ATOMIC_RELAXED, __HIP_MEMORY_SCOPE_AGENT);
    }
}

// ---------------------------------------------------------------- prep
__global__ void prep_all(const float* __restrict__ emb, const float* __restrict__ Wx0,
                         const float* __restrict__ hidden, const float* __restrict__ Wout,
                         unsigned short* embB, unsigned short* wx0cat,
                         unsigned short* WoutB,
                         unsigned short* h0bt, unsigned short* h1bfx, int* flags) {
    int job = blockIdx.y;
    int stride = gridDim.x * blockDim.x;
    int i0 = blockIdx.x * blockDim.x + threadIdx.x;
    if (job == 0) {
        for (int i = i0; i < V_ * KPAD; i += stride) {
            int v = i / KPAD, k = i - v * KPAD;
            embB[i] = (k < E_) ? f2bf(emb[v * E_ + k]) : (unsigned short)0;
        }
    } else if (job == 1) {
        for (int i = i0; i < 1536 * KPAD; i += stride) {
            int n = i / KPAD, k = i - n * KPAD;
            wx0cat[i] = (k < E_) ? f2bf(Wx0[n * E_ + k]) : (unsigned short)0;
        }
    } else if (job == 2) {
        for (int i = i0; i < 2 * BH_; i += stride) {
            if (i < BH_) h0bt[i] = f2bf(hidden[i]);
            else         h1bfx[i - BH_] = f2bf(hidden[i]);
        }
        for (int i = i0; i < NWG * 32; i += stride) flags[i] = 0;
    } else {
        for (int i = i0; i < V_ * H_; i += stride) WoutB[i] = f2bf(Wout[i]);
    }
}

// ---------------------------------------------------------------- x-side GEMM
__global__ __launch_bounds__(256) void xside_gemm(
    const int* __restrict__ inputs, const unsigned short* __restrict__ embB,
    const unsigned short* __restrict__ wx0cat, float* __restrict__ gx0) {
    int m0 = blockIdx.x * 128, n0 = blockIdx.y * 128;
    int wave = threadIdx.x >> 6, lane = threadIdx.x & 63;
    int wr = wave >> 1, wc = wave & 1;
    int am = m0 + wr * 64, bn = n0 + wc * 64;
    int lr = lane & 15, lk = (lane >> 4) * 8;

    f32x4 acc[4][4] = {};
    int id[4];
    #pragma unroll
    for (int i = 0; i < 4; ++i) id[i] = inputs[am + i * 16 + lr];

    for (int k0 = 0; k0 < KPAD; k0 += 32) {
        bf16x8 a[4], b[4];
        #pragma unroll
        for (int i = 0; i < 4; ++i)
            a[i] = *(const bf16x8*)(embB + (size_t)id[i] * KPAD + k0 + lk);
        #pragma unroll
        for (int j = 0; j < 4; ++j)
            b[j] = *(const bf16x8*)(wx0cat + (size_t)(bn + j * 16 + lr) * KPAD + k0 + lk);
        #pragma unroll
        for (int i = 0; i < 4; ++i)
            #pragma unroll
            for (int j = 0; j < 4; ++j)
                acc[i][j] = __builtin_amdgcn_mfma_f32_16x16x32_bf16(a[i], b[j], acc[i][j], 0, 0, 0);
    }
    int crow0 = (lane >> 4) * 4, ccol = lane & 15;
    #pragma unroll
    for (int i = 0; i < 4; ++i) {
        #pragma unroll
        for (int r = 0; r < 4; ++r) {
            int row = am + i * 16 + crow0 + r;
            int t = row >> 7, b = row & 127;
            #pragma unroll
            for (int j = 0; j < 4; ++j) {
                int col = bn + j * 16 + ccol;
                int g = col >> 9, h = col & 511;
                gx0[((size_t)(t * 3 + g) * 128 + b) * 512 + h] = acc[i][j][r];
            }
        }
    }
}

// ---------------------------------------------------------------- scan (r16)
__device__ __forceinline__ void bar_l0(int* flb, int wgl, int gen) {
    __syncthreads();
    if (threadIdx.x == 0)
        __hip_atomic_store(flb + wgl * 32, gen,
                           __ATOMIC_RELAXED, __HIP_MEMORY_SCOPE_AGENT);
    if (threadIdx.x < 16) {
        while (__hip_atomic_load(flb + threadIdx.x * 32, __ATOMIC_RELAXED,
                                 __HIP_MEMORY_SCOPE_AGENT) < gen)
            __builtin_amdgcn_s_sleep(1);
    }
    __syncthreads();
}

__device__ __forceinline__ void bar_l1(int* flb, int wid, int gen, int l0need) {
    __syncthreads();
    if (threadIdx.x == 0)
        __hip_atomic_store(flb + (16 + wid) * 32, gen,
                           __ATOMIC_RELAXED, __HIP_MEMORY_SCOPE_AGENT);
    if (threadIdx.x < 32) {
        while (__hip_atomic_load(flb + (16 + threadIdx.x) * 32, __ATOMIC_RELAXED,
                                 __HIP_MEMORY_SCOPE_AGENT) < gen)
            __builtin_amdgcn_s_sleep(1);
    } else if (threadIdx.x < 48) {
        while (__hip_atomic_load(flb + (threadIdx.x - 32) * 32, __ATOMIC_RELAXED,
                                 __HIP_MEMORY_SCOPE_AGENT) < l0need)
            __builtin_amdgcn_s_sleep(1);
    }
    __syncthreads();
}

__global__ __launch_bounds__(512) void scan_kernel(
    const float* __restrict__ gx0,
    const float* __restrict__ Wx, const float* __restrict__ Wh,
    const float* __restrict__ bh, const float* __restrict__ hidden,
    unsigned short* h0bt, unsigned short* rh0t, unsigned short* rh1t,
    unsigned short* h1bfx, int* flags, float* hfinal_out) {
    __shared__ unsigned short wlds[96 * 512];   // 96 KB

    const int tid = threadIdx.x;
    const int bx = blockIdx.x;
    const int cl = bx & 3;
    const int wgl = bx >> 2;
    const int lane = tid & 63;
    const int wave = tid >> 6;
    const int lr = lane & 15;
    const int hi = lane >> 4;
    const int lk8 = hi * 8;
    const int ccol = lane & 15;
    const int crow0 = hi * 4;
    const int R0 = cl * 32;

    const bool isL0 = (wgl < 16);
    const int wid = wgl - 16;
    int* flb = flags + cl * CLW * 32;

    if (isL0) {
        for (int i = tid; i < 96 * 64; i += 512) {
            int lc = i >> 6, kg = i & 63;
            int g = lc >> 5, h = (wgl << 5) + (lc & 31);
            const float* src = Wh + (size_t)(g * 512 + h) * 512 + kg * 8;
            *(bf16x8*)(wlds + lc * 512 + (kg ^ (lc & 7)) * 8) = cvt8(src);
        }
    } else {
        for (int i = tid; i < 48 * 128; i += 512) {
            int lc = i >> 7, kg = i & 127;
            int g = lc >> 4, h = (wid << 4) + (lc & 15);
            const float* src = (kg < 64)
                ? Wx + (size_t)(g * 512 + h) * 512 + kg * 8
                : Wh + (size_t)(3 * 512 * 512) + (size_t)(g * 512 + h) * 512 + (kg - 64) * 8;
            *(bf16x8*)(wlds + lc * 1024 + (kg ^ (lc & 7)) * 8) = cvt8(src);
        }
    }

    const int mt0 = wave >> 2, nt0 = wave & 3;
    const int mt1 = (wave >> 1) & 1, nt1 = wave & 1;
    float h0reg[4], freg0[4], bias_p1_0 = 0.f, bias_p2_0 = 0.f;
    float h1reg[4], freg1[4], bias_p1_1 = 0.f, bias_p2_1 = 0.f;
    bf16x8 a0keep[16];

    if (isL0) {
        const int base = wgl << 5;
        int g = nt0 >> 1;
        int hp1 = base + (nt0 & 1) * 16 + ccol;
        bias_p1_0 = bh[g * 512 + hp1];
        if (nt0 >= 2) {
            int hc = base + (nt0 - 2) * 16 + ccol;
            int rowg = R0 + mt0 * 16;
            #pragma unroll
            for (int r = 0; r < 4; ++r)
                h0reg[r] = hidden[(size_t)(rowg + crow0 + r) * 512 + hc];
            bias_p2_0 = bh[1024 + hc];
        }
    } else {
        const int base = wid << 4;
        int hc = base + ccol;
        if (wave < 4) {
            bias_p1_1 = bh[1536 + nt1 * 512 + hc];
            if (nt1 == 1) {
                int rowg = R0 + mt1 * 16;
                #pragma unroll
                for (int r = 0; r < 4; ++r)
                    h1reg[r] = hidden[(size_t)BH_ + (size_t)(rowg + crow0 + r) * 512 + hc];
                bias_p2_1 = bh[2560 + hc];
            }
        }
    }
    __syncthreads();

    if (isL0) {
        const int base = wgl << 5;
        const int rowg = R0 + mt0 * 16;
        const int hP1 = base + (nt0 & 1) * 16 + ccol;
        const int gP1 = nt0 >> 1;
        const int ntp = (nt0 >= 2) ? (nt0 - 2) : 0;
        const int hP2 = base + ntp * 16 + ccol;

        float gxn[4];
        {
            const float* gx = gx0 + (size_t)(0 * 3 + gP1) * BH_ + hP1;
            #pragma unroll
            for (int r = 0; r < 4; ++r)
                gxn[r] = gx[(rowg + crow0 + r) * 512];
        }

        for (int s = 0; s < 2 * T_; ++s) {
            bar_l0(flb, wgl, s);
            int t = s >> 1;
            float gxc[4];
            #pragma unroll
            for (int r = 0; r < 4; ++r) gxc[r] = gxn[r];
            if (s + 1 < 2 * T_) {
                int tn = (s + 1) >> 1;
                const float* gx = (((s + 1) & 1) == 0)
                    ? gx0 + (size_t)(tn * 3 + gP1) * BH_ + hP1
                    : gx0 + (size_t)(tn * 3 + 2) * BH_ + hP2;
                #pragma unroll
                for (int r = 0; r < 4; ++r)
                    gxn[r] = gx[(rowg + crow0 + r) * 512];
            }
            if ((s & 1) == 0) {
                const unsigned short* hprev = h0bt + (size_t)t * BH_;
                unsigned short* rh0 = rh0t + (size_t)t * BH_;
                bf16x8 a[16];
                #pragma unroll
                for (int ks = 0; ks < 16; ++ks)
                    a[ks] = *(const bf16x8*)(hprev + (size_t)(rowg + lr) * 512 + ks * 32 + lk8);
                f32x4 accA = {0.f, 0.f, 0.f, 0.f}, accB = {0.f, 0.f, 0.f, 0.f};
                #pragma unroll
                for (int ks = 0; ks < 16; ks += 2) {
                    int c = nt0 * 16 + lr;
                    int kgA = 4 * ks + hi, kgB = 4 * (ks + 1) + hi;
                    bf16x8 bA = *(const bf16x8*)(wlds + c * 512 + (kgA ^ (c & 7)) * 8);
                    bf16x8 bB = *(const bf16x8*)(wlds + c * 512 + (kgB ^ (c & 7)) * 8);
                    accA = __builtin_amdgcn_mfma_f32_16x16x32_bf16(a[ks], bA, accA, 0, 0, 0);
                    accB = __builtin_amdgcn_mfma_f32_16x16x32_bf16(a[ks + 1], bB, accB, 0, 0, 0);
                }
                #pragma unroll
                for (int r = 0; r < 4; ++r) {
                    int b = rowg + crow0 + r;
                    float v = accA[r] + accB[r] + gxc[r] + bias_p1_0;
                    float sg = 1.f / (1.f + __expf(-v));
                    if (nt0 < 2) {
                        float h0p = bf2f(hprev[(size_t)b * 512 + hP1]);
                        store_quad_bf16(rh0, b * 512 + hP1 - (lane & 3), sg * h0p, lane);
                    } else {
                        freg0[r] = sg;
                    }
                }
            } else if (nt0 >= 2) {
                const unsigned short* rh0 = rh0t + (size_t)t * BH_;
                unsigned short* h0nx = h0bt + (size_t)(t + 1) * BH_;
                bf16x8 a[16];
                #pragma unroll
                for (int ks = 0; ks < 16; ++ks)
                    a[ks] = *(const bf16x8*)(rh0 + (size_t)(rowg + lr) * 512 + ks * 32 + lk8);
                f32x4 accA = {0.f, 0.f, 0.f, 0.f}, accB = {0.f, 0.f, 0.f, 0.f};
                #pragma unroll
                for (int ks = 0; ks < 16; ks += 2) {
                    int c = 64 + ntp * 16 + lr;
                    int kgA = 4 * ks + hi, kgB = 4 * (ks + 1) + hi;
                    bf16x8 bA = *(const bf16x8*)(wlds + c * 512 + (kgA ^ (c & 7)) * 8);
                    bf16x8 bB = *(const bf16x8*)(wlds + c * 512 + (kgB ^ (c & 7)) * 8);
                    accA = __builtin_amdgcn_mfma_f32_16x16x32_bf16(a[ks], bA, accA, 0, 0, 0);
                    accB = __builtin_amdgcn_mfma_f32_16x16x32_bf16(a[ks + 1], bB, accB, 0, 0, 0);
                }
                #pragma unroll
                for (int r = 0; r < 4; ++r) {
                    int b = rowg + crow0 + r;
                    float v = accA[r] + accB[r] + gxc[r] + bias_p2_0;
                    float tld = tanhf(v);
                    float hn = h0reg[r] + freg0[r] * (tld - h0reg[r]);
                    h0reg[r] = hn;
                    store_quad_bf16(h0nx, b * 512 + hP2 - (lane & 3), hn, lane);
                }
            }
        }
        __syncthreads();
        if (tid == 0)
            __hip_atomic_store(flb + wgl * 32, 2 * T_,
                               __ATOMIC_RELAXED, __HIP_MEMORY_SCOPE_AGENT);
        if (nt0 >= 2) {
            #pragma unroll
            for (int r = 0; r < 4; ++r)
                hfinal_out[(size_t)(rowg + crow0 + r) * 512 + hP2] = h0reg[r];
        }
    } else {
        for (int s = 0; s < 2 * T_; ++s) {
            int tc = s >> 1;
            int l0need = ((s & 1) == 0) ? (2 * tc + 2) : 0;
            bar_l1(flb, wid, s, l0need);
            if ((s & 1) == 0) {
                if (wave < 4) {
                    const int base = wid << 4;
                    const int rowg = R0 + mt1 * 16;
                    const unsigned short* h0cur = h0bt + (size_t)(tc + 1) * BH_;
                    const unsigned short* h1prev = h1bfx + (size_t)tc * BH_;
                    unsigned short* rh1 = rh1t + (size_t)tc * BH_;
                    bf16x8 a1[16];
                    #pragma unroll
                    for (int ks = 0; ks < 16; ++ks) {
                        a0keep[ks] = *(const bf16x8*)(h0cur + (size_t)(rowg + lr) * 512 + ks * 32 + lk8);
                        a1[ks] = *(const bf16x8*)(h1prev + (size_t)(rowg + lr) * 512 + ks * 32 + lk8);
                    }
                    f32x4 accA = {0.f, 0.f, 0.f, 0.f}, accB = {0.f, 0.f, 0.f, 0.f};
                    #pragma unroll
                    for (int ks = 0; ks < 16; ++ks) {
                        int kg = 4 * ks + hi;
                        int c = nt1 * 16 + lr;
                        bf16x8 b = *(const bf16x8*)(wlds + c * 1024 + (kg ^ (c & 7)) * 8);
                        accA = __builtin_amdgcn_mfma_f32_16x16x32_bf16(a0keep[ks], b, accA, 0, 0, 0);
                    }
                    #pragma unroll
                    for (int ks = 0; ks < 16; ++ks) {
                        int kg = 64 + 4 * ks + hi;
                        int c = nt1 * 16 + lr;
                        bf16x8 b = *(const bf16x8*)(wlds + c * 1024 + (kg ^ (c & 7)) * 8);
                        accB = __builtin_amdgcn_mfma_f32_16x16x32_bf16(a1[ks], b, accB, 0, 0, 0);
                    }
                    int h = base + ccol;
                    #pragma unroll
                    for (int r = 0; r < 4; ++r) {
                        int b = rowg + crow0 + r;
                        float v = accA[r] + accB[r] + bias_p1_1;
                        float sg = 1.f / (1.f + __expf(-v));
                        if (nt1 == 0) {
                            float h1p = bf2f(h1prev[(size_t)b * 512 + h]);
                            store_quad_bf16(rh1, b * 512 + h - (lane & 3), sg * h1p, lane);
                        } else {
                            freg1[r] = sg;
                        }
                    }
                }
            } else {
                if (wave < 4 && nt1 == 1) {
                    const int base = wid << 4;
                    const int rowg = R0 + mt1 * 16;
                    const unsigned short* rh1 = rh1t + (size_t)tc * BH_;
                    unsigned short* h1nx = h1bfx + (size_t)(tc + 1) * BH_;
                    bf16x8 a1[16];
                    #pragma unroll
                    for (int ks = 0; ks < 16; ++ks)
                        a1[ks] = *(const bf16x8*)(rh1 + (size_t)(rowg + lr) * 512 + ks * 32 + lk8);
                    f32x4 accA = {0.f, 0.f, 0.f, 0.f}, accB = {0.f, 0.f, 0.f, 0.f};
                    #pragma unroll
                    for (int ks = 0; ks < 16; ++ks) {
                        int kg = 4 * ks + hi;
                        int c = 32 + lr;
                        bf16x8 b = *(const bf16x8*)(wlds + c * 1024 + (kg ^ (c & 7)) * 8);
                        accA = __builtin_amdgcn_mfma_f32_16x16x32_bf16(a0keep[ks], b, accA, 0, 0, 0);
                    }
                    #pragma unroll
                    for (int ks = 0; ks < 16; ++ks) {
                        int kg = 64 + 4 * ks + hi;
                        int c = 32 + lr;
                        bf16x8 b = *(const bf16x8*)(wlds + c * 1024 + (kg ^ (c & 7)) * 8);
                        accB = __builtin_amdgcn_mfma_f32_16x16x32_bf16(a1[ks], b, accB, 0, 0, 0);
                    }
                    int h = base + ccol;
                    #pragma unroll
                    for (int r = 0; r < 4; ++r) {
                        int b = rowg + crow0 + r;
                        float v = accA[r] + accB[r] + bias_p2_1;
                        float tld = tanhf(v);
                        float hn = h1reg[r] + freg1[r] * (tld - h1reg[r]);
                        h1reg[r] = hn;
                        store_quad_bf16(h1nx, b * 512 + h - (lane & 3), hn, lane);
                    }
                }
            }
        }
        if (wave < 4 && nt1 == 1) {
            const int base = wid << 4;
            int rowg = R0 + mt1 * 16;
            #pragma unroll
            for (int r = 0; r < 4; ++r)
                hfinal_out[(size_t)BH_ + (size_t)(rowg + crow0 + r) * 512 + base + ccol] = h1reg[r];
        }
    }
}

// ---------------------------------------------------------------- logits
// r16 structure + RFO-free C stores (paired 8B agent-scope, L2-bypass).
#define MT_ (T_ * B_ / 128)          // 35 m-tiles
#define NT_ ((V_ + 127) / 128)       // 79 n-tiles
__global__ __launch_bounds__(256) void logits_gemm(
    const unsigned short* __restrict__ A, const unsigned short* __restrict__ Bw,
    const float* __restrict__ bout, float* __restrict__ C) {
    const int nwg = MT_ * NT_;
    const int q = nwg / 8, rr = nwg % 8;
    int bid = blockIdx.x;
    int xcd = bid % 8, idx = bid / 8;
    int wgid = (xcd < rr ? xcd * (q + 1) : rr * (q + 1) + (xcd - rr) * q) + idx;
    int n0 = (wgid / MT_) * 128;
    int m0 = (wgid % MT_) * 128;

    int wave = threadIdx.x >> 6, lane = threadIdx.x & 63;
    int wr = wave >> 1, wc = wave & 1;
    int am = m0 + wr * 64, bn = n0 + wc * 64;
    int lr = lane & 15, lk = (lane >> 4) * 8;

    f32x4 acc[4][4] = {};
    bf16x8 a[4], b[4], an[4], bnx[4];
    #pragma unroll
    for (int i = 0; i < 4; ++i)
        a[i] = *(const bf16x8*)(A + (size_t)(am + i * 16 + lr) * H_ + lk);
    #pragma unroll
    for (int j = 0; j < 4; ++j) {
        int colc = bn + j * 16 + lr; if (colc >= V_) colc = V_ - 1;
        b[j] = *(const bf16x8*)(Bw + (size_t)colc * H_ + lk);
    }
    for (int k0 = 0; k0 < H_; k0 += 32) {
        if (k0 + 32 < H_) {
            #pragma unroll
            for (int i = 0; i < 4; ++i)
                an[i] = *(const bf16x8*)(A + (size_t)(am + i * 16 + lr) * H_ + k0 + 32 + lk);
            #pragma unroll
            for (int j = 0; j < 4; ++j) {
                int colc = bn + j * 16 + lr; if (colc >= V_) colc = V_ - 1;
                bnx[j] = *(const bf16x8*)(Bw + (size_t)colc * H_ + k0 + 32 + lk);
            }
        }
        #pragma unroll
        for (int i = 0; i < 4; ++i)
            #pragma unroll
            for (int j = 0; j < 4; ++j)
                acc[i][j] = __builtin_amdgcn_mfma_f32_16x16x32_bf16(a[i], b[j], acc[i][j], 0, 0, 0);
        #pragma unroll
        for (int i = 0; i < 4; ++i) { a[i] = an[i]; b[i] = bnx[i]; }
    }
    int crow0 = (lane >> 4) * 4, ccol = lane & 15;
    // V_=10000 even, pair cols (even,odd) never straddle the tail.
    #pragma unroll
    for (int j = 0; j < 4; ++j) {
        int col = bn + j * 16 + ccol;
        if (col >= V_) continue;
        float bv = bout[col];
        #pragma unroll
        for (int i = 0; i < 4; ++i) {
            #pragma unroll
            for (int r = 0; r < 4; ++r) {
                int row = am + i * 16 + crow0 + r;
                store_pair_f32(C, (size_t)row * V_ + (col & ~1),
                               acc[i][j][r] + bv, lane);
            }
        }
    }
}

// ---------------------------------------------------------------- launch
extern "C" void kernel_launch(void* const* d_in, const int* in_sizes, int n_in,
                              void* d_out, int out_size, void* d_ws, size_t ws_size,
                              hipStream_t stream) {
    const int*   inputs = (const int*)  d_in[0];
    const float* hidden = (const float*)d_in[1];
    const float* emb    = (const float*)d_in[2];
    const float* Wx0    = (const float*)d_in[3];
    const float* Wx     = (const float*)d_in[4];
    const float* Wh     = (const float*)d_in[5];
    const float* bh     = (const float*)d_in[6];
    const float* Wout   = (const float*)d_in[7];
    const float* bout   = (const float*)d_in[8];
    float* out = (float*)d_out;
    (void)in_sizes; (void)n_in; (void)out_size; (void)ws_size;

    char* ws = (char*)d_ws;
    size_t off = 0;
    auto alloc = [&](size_t bytes) -> void* {
        void* p = ws + off;
        off += (bytes + 255) & ~(size_t)255;
        return p;
    };
    unsigned short* embB   = (unsigned short*)alloc((size_t)V_ * KPAD * 2);
    unsigned short* wx0cat = (unsigned short*)alloc((size_t)1536 * KPAD * 2);
    unsigned short* WoutB  = (unsigned short*)alloc((size_t)V_ * H_ * 2);
    unsigned short* h1bfx  = (unsigned short*)alloc((size_t)(T_ + 1) * BH_ * 2);
    int* flags = (int*)alloc(NWG * 32 * 4);

    float* gx0 = out;
    unsigned short* scr = (unsigned short*)(out + (size_t)T_ * 3 * BH_);
    unsigned short* h0bt = scr;                                   // 36*BH
    unsigned short* rh0t = scr + (size_t)(T_ + 1) * BH_;          // 35*BH
    unsigned short* rh1t = scr + (size_t)(2 * T_ + 1) * BH_;      // 35*BH

    prep_all<<<dim3(1024, 4), dim3(256), 0, stream>>>(
        emb, Wx0, hidden, Wout, embB, wx0cat, WoutB, h0bt, h1bfx, flags);
    xside_gemm<<<dim3(T_, 12), dim3(256), 0, stream>>>(inputs, embB, wx0cat, gx0);
    scan_kernel<<<dim3(NWG), dim3(512), 0, stream>>>(
        gx0, Wx, Wh, bh, hidden,
        h0bt, rh0t, rh1t, h1bfx, flags,
        out + (size_t)T_ * B_ * V_);
    logits_gemm<<<dim3(MT_ * NT_), dim3(256), 0, stream>>>(
        h1bfx + BH_, WoutB, bout, out);
}